// Round 1
// baseline (642.220 us; speedup 1.0000x reference)
//
#include <hip/hip_runtime.h>
#include <hip/hip_bf16.h>

#define B_ 4
#define C_ 256
#define L_ 4096
#define G_ 32

typedef __attribute__((ext_vector_type(8))) short bf16x8;
typedef __attribute__((ext_vector_type(4))) float f32x4;
typedef __attribute__((ext_vector_type(4))) unsigned short us4;
typedef __attribute__((ext_vector_type(8))) unsigned short us8;

__device__ __forceinline__ unsigned short f2bf(float f) {
  unsigned u = __builtin_bit_cast(unsigned, f);
  u += 0x7fffu + ((u >> 16) & 1u);
  return (unsigned short)(u >> 16);
}

__device__ __forceinline__ void async_copy16(const void* g, void* l) {
  __builtin_amdgcn_global_load_lds((const __attribute__((address_space(1))) void*)g,
                                   (__attribute__((address_space(3))) void*)l, 16, 0, 0);
}

// ---------------- weight fp32 -> bf16 ----------------
__global__ void wcvt_kernel(const float* __restrict__ src, unsigned short* __restrict__ dst) {
  int i = (blockIdx.x * 256 + threadIdx.x) * 4;
  float4 v = *(const float4*)(src + i);
  us4 o;
  o[0] = f2bf(v.x); o[1] = f2bf(v.y); o[2] = f2bf(v.z); o[3] = f2bf(v.w);
  *(us4*)(dst + i) = o;
}

// ---------------- GroupNorm stats ----------------
__global__ void gn_stats_kernel(const float* __restrict__ x, float2* __restrict__ stats) {
  int bg = blockIdx.x;                       // b*32+g
  const float* xp = x + (size_t)bg * 8 * L_; // group rows are contiguous
  float s = 0.f, ss = 0.f;
  for (int i = threadIdx.x * 4; i < 8 * L_; i += 1024) {
    float4 v = *(const float4*)(xp + i);
    s += v.x + v.y + v.z + v.w;
    ss += v.x * v.x + v.y * v.y + v.z * v.z + v.w * v.w;
  }
#pragma unroll
  for (int m = 1; m < 64; m <<= 1) { s += __shfl_xor(s, m); ss += __shfl_xor(ss, m); }
  __shared__ float red[8];
  int w = threadIdx.x >> 6;
  if ((threadIdx.x & 63) == 0) { red[w] = s; red[4 + w] = ss; }
  __syncthreads();
  if (threadIdx.x == 0) {
    s = red[0] + red[1] + red[2] + red[3];
    ss = red[4] + red[5] + red[6] + red[7];
    const float inv_n = 1.f / (8.f * L_);
    float mean = s * inv_n;
    float var = ss * inv_n - mean * mean;
    stats[bg] = make_float2(mean, rsqrtf(var + 1e-6f));
  }
}

// ---------------- GroupNorm apply -> xn_t [b][l][c] bf16 ----------------
__global__ void gn_apply_kernel(const float* __restrict__ x, const float* __restrict__ gw,
                                const float* __restrict__ gb, const float2* __restrict__ stats,
                                unsigned short* __restrict__ xn_t) {
  int b = blockIdx.x >> 9;
  int l0 = (blockIdx.x & 511) * 8;
  int c8 = threadIdx.x & 31;   // == group index (8 ch per group)
  int dl = threadIdx.x >> 5;   // 0..7
  int l = l0 + dl;
  int c0 = c8 * 8;
  float2 st = stats[b * 32 + c8];
  const float* xp = x + ((size_t)b * C_ + c0) * L_ + l;
  us8 o;
#pragma unroll
  for (int j = 0; j < 8; ++j) {
    float v = (xp[(size_t)j * L_] - st.x) * st.y * gw[c0 + j] + gb[c0 + j];
    o[j] = f2bf(v);
  }
  *(us8*)(xn_t + ((size_t)b * L_ + l) * C_ + c0) = o;
}

// ---------------- QKV GEMM: [o][l] = W[o][c] * xn[c][l]; q,k -> [l][o], v -> [o][l] ----------------
__global__ __launch_bounds__(256) void qkv_gemm_kernel(
    const unsigned short* __restrict__ wq, const unsigned short* __restrict__ wk,
    const unsigned short* __restrict__ wv, const float* __restrict__ qbias,
    const float* __restrict__ kbias, const float* __restrict__ vbias,
    const unsigned short* __restrict__ xn, unsigned short* __restrict__ qt,
    unsigned short* __restrict__ kt, unsigned short* __restrict__ vt) {
  int id = blockIdx.x;
  int nt = id & 63, mt = (id >> 6) & 3, b = (id >> 8) & 3, mat = id >> 10;
  const unsigned short* W = (mat == 0) ? wq : ((mat == 1) ? wk : wv);
  const float* bias = (mat == 0) ? qbias : ((mat == 1) ? kbias : vbias);
  int lane = threadIdx.x & 63, wid = threadIdx.x >> 6;
  int ln = lane & 15, lq = lane >> 4;
  int m0 = mt * 64 + wid * 16;
  int n0 = nt * 64;
  const unsigned short* xb = xn + (size_t)b * L_ * C_;
  bf16x8 a[8];
  const unsigned short* arow = W + (m0 + ln) * C_ + lq * 8;
#pragma unroll
  for (int ks = 0; ks < 8; ++ks) a[ks] = *(const bf16x8*)(arow + ks * 32);
  f32x4 acc[4];
#pragma unroll
  for (int t = 0; t < 4; ++t) {
    f32x4 c = {0.f, 0.f, 0.f, 0.f};
    const unsigned short* brow = xb + (size_t)(n0 + 16 * t + ln) * C_ + lq * 8;
#pragma unroll
    for (int ks = 0; ks < 8; ++ks) {
      bf16x8 bf = *(const bf16x8*)(brow + ks * 32);
      c = __builtin_amdgcn_mfma_f32_16x16x32_bf16(a[ks], bf, c, 0, 0, 0);
    }
    acc[t] = c;
  }
  int o0 = m0 + lq * 4;   // D row = o, D col = l
  if (mat < 2) {
    unsigned short* dst = ((mat == 0) ? qt : kt) + (size_t)b * L_ * C_;
    float bv[4];
#pragma unroll
    for (int r = 0; r < 4; ++r) bv[r] = bias[o0 + r];
#pragma unroll
    for (int t = 0; t < 4; ++t) {
      int l = n0 + 16 * t + ln;
      us4 pk;
#pragma unroll
      for (int r = 0; r < 4; ++r) pk[r] = f2bf(acc[t][r] + bv[r]);
      *(us4*)(dst + (size_t)l * C_ + o0) = pk;
    }
  } else {
    unsigned short* dst = vt + (size_t)b * C_ * L_;
#pragma unroll
    for (int r = 0; r < 4; ++r) {
      float bvr = bias[o0 + r];
#pragma unroll
      for (int t = 0; t < 4; ++t)
        dst[(size_t)(o0 + r) * L_ + n0 + 16 * t + ln] = f2bf(acc[t][r] + bvr);
    }
  }
}

// ---------------- Flash attention ----------------
// q,k in [b][l][c] bf16; v in [b][c][l] bf16; out ot [b][l][c] bf16
__global__ __launch_bounds__(256) void attn_kernel(
    const unsigned short* __restrict__ qt, const unsigned short* __restrict__ kt,
    const unsigned short* __restrict__ vt, unsigned short* __restrict__ ot) {
  __shared__ int4 KlBuf[2048];                               // 32 KB K tile, swizzled
  __shared__ __attribute__((aligned(16))) unsigned short Pl[4][16 * 72]; // per-wave P, pad 72
  unsigned short* Kl = (unsigned short*)KlBuf;

  int swz = ((blockIdx.x & 7) << 5) | (blockIdx.x >> 3);     // XCD-chunked (256 % 8 == 0, bijective)
  int b = swz >> 6, it = swz & 63;
  int i0 = it * 64;
  int lane = threadIdx.x & 63, wid = threadIdx.x >> 6;
  int ln = lane & 15, lq = lane >> 4;
  const unsigned short* qb_ = qt + (size_t)b * L_ * C_;
  const unsigned short* kb_ = kt + (size_t)b * L_ * C_;
  const unsigned short* vb_ = vt + (size_t)b * C_ * L_;
  int iw = i0 + wid * 16;

  bf16x8 qf[8];
#pragma unroll
  for (int ks = 0; ks < 8; ++ks)
    qf[ks] = *(const bf16x8*)(qb_ + (size_t)(iw + ln) * C_ + ks * 32 + lq * 8);

  f32x4 oacc[16];
#pragma unroll
  for (int ct = 0; ct < 16; ++ct) oacc[ct] = {0.f, 0.f, 0.f, 0.f};
  float m_run[4] = {-3e38f, -3e38f, -3e38f, -3e38f};
  float l_run[4] = {0.f, 0.f, 0.f, 0.f};

  const int colb = (lane & 31) * 16;      // byte col within row for K staging
  const int subr = lane >> 5;             // 0/1
  auto loadK = [&](int j0) {
#pragma unroll
    for (int q = 0; q < 8; ++q) {
      int chunk = wid * 8 + q;            // 1 KB chunks, 2 rows each
      int row = chunk * 2 + subr;
      int gcol = colb ^ ((row & 7) << 4); // pre-swizzle SOURCE, LDS stays linear
      async_copy16((const char*)kb_ + (size_t)(j0 + row) * (C_ * 2) + gcol,
                   (char*)Kl + chunk * 1024);
    }
  };

  loadK(0);
  const float SCALE = 0.0625f;            // C^-0.5
  const float LOG2E = 1.44269504f;
  unsigned short* Pw = Pl[wid];
  const int kswz = (ln & 7) << 4;         // read-side swizzle (row&7 == ln&7)

#pragma unroll 1
  for (int jt = 0; jt < 64; ++jt) {
    int j0 = jt * 64;
    asm volatile("s_waitcnt vmcnt(0)" ::: "memory");
    __syncthreads();                      // K(jt) staged

    f32x4 s4[4];
#pragma unroll
    for (int t = 0; t < 4; ++t) s4[t] = {0.f, 0.f, 0.f, 0.f};
#pragma unroll
    for (int ks = 0; ks < 8; ++ks) {
#pragma unroll
      for (int t = 0; t < 4; ++t) {
        int row = 16 * t + ln;
        const bf16x8 kf = *(const bf16x8*)((const char*)Kl + row * 512 + ((ks * 64 + lq * 16) ^ kswz));
        s4[t] = __builtin_amdgcn_mfma_f32_16x16x32_bf16(qf[ks], kf, s4[t], 0, 0, 0);
      }
    }
    __syncthreads();                      // all QK reads done
    if (jt + 1 < 64) loadK(j0 + 64);      // prefetch hides under softmax+PV

#pragma unroll
    for (int t = 0; t < 4; ++t) s4[t] *= SCALE;
    float p[4][4];
    float alpha[4];
#pragma unroll
    for (int r = 0; r < 4; ++r) {
      float mt_ = fmaxf(fmaxf(s4[0][r], s4[1][r]), fmaxf(s4[2][r], s4[3][r]));
      mt_ = fmaxf(mt_, __shfl_xor(mt_, 1));
      mt_ = fmaxf(mt_, __shfl_xor(mt_, 2));
      mt_ = fmaxf(mt_, __shfl_xor(mt_, 4));
      mt_ = fmaxf(mt_, __shfl_xor(mt_, 8));
      float mn = fmaxf(m_run[r], mt_);
      alpha[r] = exp2f((m_run[r] - mn) * LOG2E);
      m_run[r] = mn;
      float ls = 0.f;
#pragma unroll
      for (int t = 0; t < 4; ++t) {
        float pv = exp2f((s4[t][r] - mn) * LOG2E);
        p[t][r] = pv; ls += pv;
      }
      ls += __shfl_xor(ls, 1); ls += __shfl_xor(ls, 2);
      ls += __shfl_xor(ls, 4); ls += __shfl_xor(ls, 8);
      l_run[r] = l_run[r] * alpha[r] + ls;
    }
#pragma unroll
    for (int ct = 0; ct < 16; ++ct)
#pragma unroll
      for (int r = 0; r < 4; ++r) oacc[ct][r] *= alpha[r];

#pragma unroll
    for (int t = 0; t < 4; ++t)
#pragma unroll
      for (int r = 0; r < 4; ++r)
        Pw[(4 * lq + r) * 72 + 16 * t + ln] = f2bf(p[t][r]);
    asm volatile("s_waitcnt lgkmcnt(0)" ::: "memory");  // wave-local P visible

#pragma unroll
    for (int ks2 = 0; ks2 < 2; ++ks2) {
      bf16x8 pa = *(const bf16x8*)(Pw + ln * 72 + ks2 * 32 + lq * 8);
#pragma unroll
      for (int ct = 0; ct < 16; ++ct) {
        const bf16x8 vf = *(const bf16x8*)(vb_ + (size_t)(16 * ct + ln) * L_ + j0 + ks2 * 32 + lq * 8);
        oacc[ct] = __builtin_amdgcn_mfma_f32_16x16x32_bf16(pa, vf, oacc[ct], 0, 0, 0);
      }
    }
  }

  unsigned short* ob = ot + (size_t)b * L_ * C_;
  float inv[4];
#pragma unroll
  for (int r = 0; r < 4; ++r) inv[r] = 1.f / l_run[r];
#pragma unroll
  for (int ct = 0; ct < 16; ++ct)
#pragma unroll
    for (int r = 0; r < 4; ++r)
      ob[(size_t)(iw + 4 * lq + r) * C_ + 16 * ct + ln] = f2bf(oacc[ct][r] * inv[r]);
}

// ---------------- proj GEMM + bias + residual (fp32 out) ----------------
__global__ __launch_bounds__(256) void proj_kernel(
    const unsigned short* __restrict__ wp, const float* __restrict__ pbias,
    const unsigned short* __restrict__ ot, const float* __restrict__ x,
    float* __restrict__ out) {
  int id = blockIdx.x;
  int nt = id & 63, mt = (id >> 6) & 3, b = id >> 8;
  int lane = threadIdx.x & 63, wid = threadIdx.x >> 6;
  int ln = lane & 15, lq = lane >> 4;
  int m0 = mt * 64 + wid * 16;
  int n0 = nt * 64;
  const unsigned short* ob = ot + (size_t)b * L_ * C_;
  bf16x8 a[8];
  const unsigned short* arow = wp + (m0 + ln) * C_ + lq * 8;
#pragma unroll
  for (int ks = 0; ks < 8; ++ks) a[ks] = *(const bf16x8*)(arow + ks * 32);
  f32x4 acc[4];
#pragma unroll
  for (int t = 0; t < 4; ++t) {
    f32x4 c = {0.f, 0.f, 0.f, 0.f};
    const unsigned short* brow = ob + (size_t)(n0 + 16 * t + ln) * C_ + lq * 8;
#pragma unroll
    for (int ks = 0; ks < 8; ++ks) {
      bf16x8 bf = *(const bf16x8*)(brow + ks * 32);
      c = __builtin_amdgcn_mfma_f32_16x16x32_bf16(a[ks], bf, c, 0, 0, 0);
    }
    acc[t] = c;
  }
  int o0 = m0 + lq * 4;
#pragma unroll
  for (int r = 0; r < 4; ++r) {
    float bvr = pbias[o0 + r];
    const float* xrow = x + ((size_t)b * C_ + o0 + r) * L_;
    float* orow = out + ((size_t)b * C_ + o0 + r) * L_;
#pragma unroll
    for (int t = 0; t < 4; ++t) {
      int l = n0 + 16 * t + ln;
      orow[l] = xrow[l] + acc[t][r] + bvr;
    }
  }
}

extern "C" void kernel_launch(void* const* d_in, const int* in_sizes, int n_in,
                              void* d_out, int out_size, void* d_ws, size_t ws_size,
                              hipStream_t stream) {
  const float* x   = (const float*)d_in[0];
  const float* gnw = (const float*)d_in[1];
  const float* gnb = (const float*)d_in[2];
  const float* qw  = (const float*)d_in[3];
  const float* qb  = (const float*)d_in[4];
  const float* kw  = (const float*)d_in[5];
  const float* kb  = (const float*)d_in[6];
  const float* vw  = (const float*)d_in[7];
  const float* vb  = (const float*)d_in[8];
  const float* pw  = (const float*)d_in[9];
  const float* pb  = (const float*)d_in[10];
  float* out = (float*)d_out;

  unsigned short* ws = (unsigned short*)d_ws;
  const size_t SZ = (size_t)B_ * L_ * C_;
  unsigned short* xn_t = ws;            // [b][l][c] bf16
  unsigned short* qt   = xn_t + SZ;     // [b][l][c]
  unsigned short* kt   = qt + SZ;       // [b][l][c]
  unsigned short* vt   = kt + SZ;       // [b][c][l]
  unsigned short* ot   = vt + SZ;       // [b][l][c]
  unsigned short* wqb  = ot + SZ;
  unsigned short* wkb  = wqb + C_ * C_;
  unsigned short* wvb  = wkb + C_ * C_;
  unsigned short* wpb  = wvb + C_ * C_;
  float2* stats = (float2*)(wpb + C_ * C_);

  wcvt_kernel<<<64, 256, 0, stream>>>(qw, wqb);
  wcvt_kernel<<<64, 256, 0, stream>>>(kw, wkb);
  wcvt_kernel<<<64, 256, 0, stream>>>(vw, wvb);
  wcvt_kernel<<<64, 256, 0, stream>>>(pw, wpb);
  gn_stats_kernel<<<B_ * G_, 256, 0, stream>>>(x, stats);
  gn_apply_kernel<<<B_ * (L_ / 8), 256, 0, stream>>>(x, gnw, gnb, stats, xn_t);
  qkv_gemm_kernel<<<3072, 256, 0, stream>>>(wqb, wkb, wvb, qb, kb, vb, xn_t, qt, kt, vt);
  attn_kernel<<<256, 256, 0, stream>>>(qt, kt, vt, ot);
  proj_kernel<<<1024, 256, 0, stream>>>(wpb, pb, ot, x, out);
}

// Round 2
// 326.422 us; speedup vs baseline: 1.9675x; 1.9675x over previous
//
#include <hip/hip_runtime.h>
#include <hip/hip_bf16.h>

#define B_ 4
#define C_ 256
#define L_ 4096
#define G_ 32

typedef __attribute__((ext_vector_type(8))) short bf16x8;
typedef __attribute__((ext_vector_type(4))) float f32x4;
typedef __attribute__((ext_vector_type(4))) unsigned short us4;
typedef __attribute__((ext_vector_type(8))) unsigned short us8;

__device__ __forceinline__ unsigned short f2bf(float f) {
  unsigned u = __builtin_bit_cast(unsigned, f);
  u += 0x7fffu + ((u >> 16) & 1u);
  return (unsigned short)(u >> 16);
}

__device__ __forceinline__ void async_copy16(const void* g, void* l) {
  __builtin_amdgcn_global_load_lds((const __attribute__((address_space(1))) void*)g,
                                   (__attribute__((address_space(3))) void*)l, 16, 0, 0);
}

// ---------------- weight fp32 -> bf16 ----------------
__global__ void wcvt_kernel(const float* __restrict__ src, unsigned short* __restrict__ dst) {
  int i = (blockIdx.x * 256 + threadIdx.x) * 4;
  float4 v = *(const float4*)(src + i);
  us4 o;
  o[0] = f2bf(v.x); o[1] = f2bf(v.y); o[2] = f2bf(v.z); o[3] = f2bf(v.w);
  *(us4*)(dst + i) = o;
}

// ---------------- GroupNorm stats ----------------
__global__ void gn_stats_kernel(const float* __restrict__ x, float2* __restrict__ stats) {
  int bg = blockIdx.x;                       // b*32+g
  const float* xp = x + (size_t)bg * 8 * L_; // group rows are contiguous
  float s = 0.f, ss = 0.f;
  for (int i = threadIdx.x * 4; i < 8 * L_; i += 1024) {
    float4 v = *(const float4*)(xp + i);
    s += v.x + v.y + v.z + v.w;
    ss += v.x * v.x + v.y * v.y + v.z * v.z + v.w * v.w;
  }
#pragma unroll
  for (int m = 1; m < 64; m <<= 1) { s += __shfl_xor(s, m); ss += __shfl_xor(ss, m); }
  __shared__ float red[8];
  int w = threadIdx.x >> 6;
  if ((threadIdx.x & 63) == 0) { red[w] = s; red[4 + w] = ss; }
  __syncthreads();
  if (threadIdx.x == 0) {
    s = red[0] + red[1] + red[2] + red[3];
    ss = red[4] + red[5] + red[6] + red[7];
    const float inv_n = 1.f / (8.f * L_);
    float mean = s * inv_n;
    float var = ss * inv_n - mean * mean;
    stats[bg] = make_float2(mean, rsqrtf(var + 1e-6f));
  }
}

// ---------------- GroupNorm apply -> xn_t [b][l][c] bf16 ----------------
__global__ void gn_apply_kernel(const float* __restrict__ x, const float* __restrict__ gw,
                                const float* __restrict__ gb, const float2* __restrict__ stats,
                                unsigned short* __restrict__ xn_t) {
  int b = blockIdx.x >> 9;
  int l0 = (blockIdx.x & 511) * 8;
  int c8 = threadIdx.x & 31;   // == group index (8 ch per group)
  int dl = threadIdx.x >> 5;   // 0..7
  int l = l0 + dl;
  int c0 = c8 * 8;
  float2 st = stats[b * 32 + c8];
  const float* xp = x + ((size_t)b * C_ + c0) * L_ + l;
  us8 o;
#pragma unroll
  for (int j = 0; j < 8; ++j) {
    float v = (xp[(size_t)j * L_] - st.x) * st.y * gw[c0 + j] + gb[c0 + j];
    o[j] = f2bf(v);
  }
  *(us8*)(xn_t + ((size_t)b * L_ + l) * C_ + c0) = o;
}

// ---------------- QKV GEMM: [o][l] = W[o][c] * xn[c][l]; q,k -> [l][o], v -> [o][l] ----------------
__global__ __launch_bounds__(256) void qkv_gemm_kernel(
    const unsigned short* __restrict__ wq, const unsigned short* __restrict__ wk,
    const unsigned short* __restrict__ wv, const float* __restrict__ qbias,
    const float* __restrict__ kbias, const float* __restrict__ vbias,
    const unsigned short* __restrict__ xn, unsigned short* __restrict__ qt,
    unsigned short* __restrict__ kt, unsigned short* __restrict__ vt) {
  int id = blockIdx.x;
  int nt = id & 63, mt = (id >> 6) & 3, b = (id >> 8) & 3, mat = id >> 10;
  const unsigned short* W = (mat == 0) ? wq : ((mat == 1) ? wk : wv);
  const float* bias = (mat == 0) ? qbias : ((mat == 1) ? kbias : vbias);
  int lane = threadIdx.x & 63, wid = threadIdx.x >> 6;
  int ln = lane & 15, lq = lane >> 4;
  int m0 = mt * 64 + wid * 16;
  int n0 = nt * 64;
  const unsigned short* xb = xn + (size_t)b * L_ * C_;
  bf16x8 a[8];
  const unsigned short* arow = W + (m0 + ln) * C_ + lq * 8;
#pragma unroll
  for (int ks = 0; ks < 8; ++ks) a[ks] = *(const bf16x8*)(arow + ks * 32);
  f32x4 acc[4];
#pragma unroll
  for (int t = 0; t < 4; ++t) {
    f32x4 c = {0.f, 0.f, 0.f, 0.f};
    const unsigned short* brow = xb + (size_t)(n0 + 16 * t + ln) * C_ + lq * 8;
#pragma unroll
    for (int ks = 0; ks < 8; ++ks) {
      bf16x8 bf = *(const bf16x8*)(brow + ks * 32);
      c = __builtin_amdgcn_mfma_f32_16x16x32_bf16(a[ks], bf, c, 0, 0, 0);
    }
    acc[t] = c;
  }
  int o0 = m0 + lq * 4;   // D row = o, D col = l
  if (mat < 2) {
    unsigned short* dst = ((mat == 0) ? qt : kt) + (size_t)b * L_ * C_;
    float bv[4];
#pragma unroll
    for (int r = 0; r < 4; ++r) bv[r] = bias[o0 + r];
#pragma unroll
    for (int t = 0; t < 4; ++t) {
      int l = n0 + 16 * t + ln;
      us4 pk;
#pragma unroll
      for (int r = 0; r < 4; ++r) pk[r] = f2bf(acc[t][r] + bv[r]);
      *(us4*)(dst + (size_t)l * C_ + o0) = pk;
    }
  } else {
    unsigned short* dst = vt + (size_t)b * C_ * L_;
#pragma unroll
    for (int r = 0; r < 4; ++r) {
      float bvr = bias[o0 + r];
#pragma unroll
      for (int t = 0; t < 4; ++t)
        dst[(size_t)(o0 + r) * L_ + n0 + 16 * t + ln] = f2bf(acc[t][r] + bvr);
    }
  }
}

// ---------------- Flash attention (pipelined, K dbuf + V LDS, counted vmcnt) ----------------
// q,k in [b][l][c] bf16; v in [b][c][l] bf16; out ot [b][l][c] bf16
__global__ __launch_bounds__(256) void attn_kernel(
    const unsigned short* __restrict__ qt, const unsigned short* __restrict__ kt,
    const unsigned short* __restrict__ vt, unsigned short* __restrict__ ot) {
  __shared__ __attribute__((aligned(16))) unsigned short Kl[2][16384]; // 2 x 32 KB, swizzled
  __shared__ __attribute__((aligned(16))) unsigned short Vl[16384];    // 32 KB, swizzled
  __shared__ __attribute__((aligned(16))) unsigned short Pl[4][16 * 72];

  int swz = ((blockIdx.x & 7) << 5) | (blockIdx.x >> 3);  // XCD-chunked, bijective (256%8==0)
  int b = swz >> 6, it = swz & 63;
  int i0 = it * 64;
  int lane = threadIdx.x & 63, wid = threadIdx.x >> 6;
  int ln = lane & 15, lq = lane >> 4;
  const unsigned short* qb_ = qt + (size_t)b * L_ * C_;
  const unsigned short* kb_ = kt + (size_t)b * L_ * C_;
  const unsigned short* vb_ = vt + (size_t)b * C_ * L_;
  int iw = i0 + wid * 16;

  bf16x8 qf[8];
#pragma unroll
  for (int ks = 0; ks < 8; ++ks)
    qf[ks] = *(const bf16x8*)(qb_ + (size_t)(iw + ln) * C_ + ks * 32 + lq * 8);

  f32x4 oacc[16];
#pragma unroll
  for (int ct = 0; ct < 16; ++ct) oacc[ct] = {0.f, 0.f, 0.f, 0.f};
  float m_run[4] = {-3e38f, -3e38f, -3e38f, -3e38f};
  float l_run[4] = {0.f, 0.f, 0.f, 0.f};

  // --- K staging: 64 rows x 512B, 8 insts/wave (1KB each = 2 rows) ---
  const int colb = (lane & 31) * 16;
  const int subr = lane >> 5;
  auto loadK = [&](int j0, unsigned short* Kb) {
#pragma unroll
    for (int q = 0; q < 8; ++q) {
      int chunk = wid * 8 + q;
      int row = chunk * 2 + subr;
      int gcol = colb ^ ((row & 7) << 4);     // pre-swizzle SOURCE, LDS dest linear
      async_copy16((const char*)kb_ + (size_t)(j0 + row) * 512 + gcol,
                   (char*)Kb + chunk * 1024);
    }
  };
  // --- V staging: 256 c-rows x 128B, 8 insts/wave (1KB each = 8 rows) ---
  const int vslot = lane & 7;
  const int vsub = lane >> 3;                  // 0..7 row-in-chunk
  auto loadV = [&](int j0) {
#pragma unroll
    for (int q = 0; q < 8; ++q) {
      int chunk = wid * 8 + q;
      int row = chunk * 8 + vsub;              // channel row
      int gcol = (vslot * 16) ^ ((vsub & 7) << 4);
      async_copy16((const char*)vb_ + (size_t)row * (L_ * 2) + (size_t)j0 * 2 + gcol,
                   (char*)Vl + chunk * 1024);
    }
  };

  loadK(0, Kl[0]);
  loadV(0);

  const float SCALE = 0.0625f;            // C^-0.5
  const float LOG2E = 1.44269504f;
  unsigned short* Pw = Pl[wid];
  const int kswz = (ln & 7) << 4;
  int cur = 0;

#pragma unroll 1
  for (int jt = 0; jt < 64; ++jt) {
    int j1 = ((jt + 1) & 63) * 64;        // wrap keeps vmcnt counts uniform

    // K(jt) is the 8 oldest outstanding loads; V(jt) (8) stays in flight
    asm volatile("s_waitcnt vmcnt(8)" ::: "memory");
    __builtin_amdgcn_sched_barrier(0);
    __builtin_amdgcn_s_barrier();         // K tile ready everywhere; old K buffer free
    __builtin_amdgcn_sched_barrier(0);

    loadK(j1, Kl[cur ^ 1]);               // hides under QK+softmax+PV

    const unsigned short* Kb = Kl[cur];
    f32x4 s4[4];
#pragma unroll
    for (int t = 0; t < 4; ++t) s4[t] = {0.f, 0.f, 0.f, 0.f};
#pragma unroll
    for (int ks = 0; ks < 8; ++ks) {
#pragma unroll
      for (int t = 0; t < 4; ++t) {
        int row = 16 * t + ln;
        const bf16x8 kf = *(const bf16x8*)((const char*)Kb + row * 512 + ((ks * 64 + lq * 16) ^ kswz));
        s4[t] = __builtin_amdgcn_mfma_f32_16x16x32_bf16(qf[ks], kf, s4[t], 0, 0, 0);
      }
    }

#pragma unroll
    for (int t = 0; t < 4; ++t) s4[t] *= SCALE;
    float p[4][4];
    float alpha[4];
#pragma unroll
    for (int r = 0; r < 4; ++r) {
      float mt_ = fmaxf(fmaxf(s4[0][r], s4[1][r]), fmaxf(s4[2][r], s4[3][r]));
      mt_ = fmaxf(mt_, __shfl_xor(mt_, 1));
      mt_ = fmaxf(mt_, __shfl_xor(mt_, 2));
      mt_ = fmaxf(mt_, __shfl_xor(mt_, 4));
      mt_ = fmaxf(mt_, __shfl_xor(mt_, 8));
      float mn = fmaxf(m_run[r], mt_);
      alpha[r] = exp2f((m_run[r] - mn) * LOG2E);
      m_run[r] = mn;
      float ls = 0.f;
#pragma unroll
      for (int t = 0; t < 4; ++t) {
        float pv = exp2f((s4[t][r] - mn) * LOG2E);
        p[t][r] = pv; ls += pv;
      }
      ls += __shfl_xor(ls, 1); ls += __shfl_xor(ls, 2);
      ls += __shfl_xor(ls, 4); ls += __shfl_xor(ls, 8);
      l_run[r] = l_run[r] * alpha[r] + ls;
    }
#pragma unroll
    for (int ct = 0; ct < 16; ++ct)
#pragma unroll
      for (int r = 0; r < 4; ++r) oacc[ct][r] *= alpha[r];

#pragma unroll
    for (int t = 0; t < 4; ++t)
#pragma unroll
      for (int r = 0; r < 4; ++r)
        Pw[(4 * lq + r) * 72 + 16 * t + ln] = f2bf(p[t][r]);
    asm volatile("s_waitcnt lgkmcnt(0)" ::: "memory");  // wave-local P visible
    __builtin_amdgcn_sched_barrier(0);

    bf16x8 pa0 = *(const bf16x8*)(Pw + ln * 72 + lq * 8);
    bf16x8 pa1 = *(const bf16x8*)(Pw + ln * 72 + 32 + lq * 8);

    // V(jt) is now the 8 oldest outstanding; K(jt+1) (8) stays in flight
    asm volatile("s_waitcnt vmcnt(8)" ::: "memory");
    __builtin_amdgcn_sched_barrier(0);
    __builtin_amdgcn_s_barrier();         // V tile ready everywhere
    __builtin_amdgcn_sched_barrier(0);

#pragma unroll
    for (int ct = 0; ct < 16; ++ct) {
      int row = 16 * ct + ln;
      const bf16x8 vf0 = *(const bf16x8*)((const char*)Vl + row * 128 + ((lq * 16) ^ kswz));
      oacc[ct] = __builtin_amdgcn_mfma_f32_16x16x32_bf16(pa0, vf0, oacc[ct], 0, 0, 0);
      const bf16x8 vf1 = *(const bf16x8*)((const char*)Vl + row * 128 + ((64 + lq * 16) ^ kswz));
      oacc[ct] = __builtin_amdgcn_mfma_f32_16x16x32_bf16(pa1, vf1, oacc[ct], 0, 0, 0);
    }

    __builtin_amdgcn_sched_barrier(0);
    __builtin_amdgcn_s_barrier();         // all PV reads of Vl done -> safe to overwrite
    __builtin_amdgcn_sched_barrier(0);
    loadV(j1);                            // hides under next QK phase

    cur ^= 1;
  }

  asm volatile("s_waitcnt vmcnt(0)" ::: "memory");  // drain wrap staging

  unsigned short* ob = ot + (size_t)b * L_ * C_;
  float inv[4];
#pragma unroll
  for (int r = 0; r < 4; ++r) inv[r] = 1.f / l_run[r];
#pragma unroll
  for (int ct = 0; ct < 16; ++ct)
#pragma unroll
    for (int r = 0; r < 4; ++r)
      ob[(size_t)(iw + 4 * lq + r) * C_ + 16 * ct + ln] = f2bf(oacc[ct][r] * inv[r]);
}

// ---------------- proj GEMM + bias + residual (fp32 out) ----------------
__global__ __launch_bounds__(256) void proj_kernel(
    const unsigned short* __restrict__ wp, const float* __restrict__ pbias,
    const unsigned short* __restrict__ ot, const float* __restrict__ x,
    float* __restrict__ out) {
  int id = blockIdx.x;
  int nt = id & 63, mt = (id >> 6) & 3, b = id >> 8;
  int lane = threadIdx.x & 63, wid = threadIdx.x >> 6;
  int ln = lane & 15, lq = lane >> 4;
  int m0 = mt * 64 + wid * 16;
  int n0 = nt * 64;
  const unsigned short* ob = ot + (size_t)b * L_ * C_;
  bf16x8 a[8];
  const unsigned short* arow = wp + (m0 + ln) * C_ + lq * 8;
#pragma unroll
  for (int ks = 0; ks < 8; ++ks) a[ks] = *(const bf16x8*)(arow + ks * 32);
  f32x4 acc[4];
#pragma unroll
  for (int t = 0; t < 4; ++t) {
    f32x4 c = {0.f, 0.f, 0.f, 0.f};
    const unsigned short* brow = ob + (size_t)(n0 + 16 * t + ln) * C_ + lq * 8;
#pragma unroll
    for (int ks = 0; ks < 8; ++ks) {
      bf16x8 bf = *(const bf16x8*)(brow + ks * 32);
      c = __builtin_amdgcn_mfma_f32_16x16x32_bf16(a[ks], bf, c, 0, 0, 0);
    }
    acc[t] = c;
  }
  int o0 = m0 + lq * 4;
#pragma unroll
  for (int r = 0; r < 4; ++r) {
    float bvr = pbias[o0 + r];
    const float* xrow = x + ((size_t)b * C_ + o0 + r) * L_;
    float* orow = out + ((size_t)b * C_ + o0 + r) * L_;
#pragma unroll
    for (int t = 0; t < 4; ++t) {
      int l = n0 + 16 * t + ln;
      orow[l] = xrow[l] + acc[t][r] + bvr;
    }
  }
}

extern "C" void kernel_launch(void* const* d_in, const int* in_sizes, int n_in,
                              void* d_out, int out_size, void* d_ws, size_t ws_size,
                              hipStream_t stream) {
  const float* x   = (const float*)d_in[0];
  const float* gnw = (const float*)d_in[1];
  const float* gnb = (const float*)d_in[2];
  const float* qw  = (const float*)d_in[3];
  const float* qb  = (const float*)d_in[4];
  const float* kw  = (const float*)d_in[5];
  const float* kb  = (const float*)d_in[6];
  const float* vw  = (const float*)d_in[7];
  const float* vb  = (const float*)d_in[8];
  const float* pw  = (const float*)d_in[9];
  const float* pb  = (const float*)d_in[10];
  float* out = (float*)d_out;

  unsigned short* ws = (unsigned short*)d_ws;
  const size_t SZ = (size_t)B_ * L_ * C_;
  unsigned short* xn_t = ws;            // [b][l][c] bf16
  unsigned short* qt   = xn_t + SZ;     // [b][l][c]
  unsigned short* kt   = qt + SZ;       // [b][l][c]
  unsigned short* vt   = kt + SZ;       // [b][c][l]
  unsigned short* ot   = vt + SZ;       // [b][l][c]
  unsigned short* wqb  = ot + SZ;
  unsigned short* wkb  = wqb + C_ * C_;
  unsigned short* wvb  = wkb + C_ * C_;
  unsigned short* wpb  = wvb + C_ * C_;
  float2* stats = (float2*)(wpb + C_ * C_);

  wcvt_kernel<<<64, 256, 0, stream>>>(qw, wqb);
  wcvt_kernel<<<64, 256, 0, stream>>>(kw, wkb);
  wcvt_kernel<<<64, 256, 0, stream>>>(vw, wvb);
  wcvt_kernel<<<64, 256, 0, stream>>>(pw, wpb);
  gn_stats_kernel<<<B_ * G_, 256, 0, stream>>>(x, stats);
  gn_apply_kernel<<<B_ * (L_ / 8), 256, 0, stream>>>(x, gnw, gnb, stats, xn_t);
  qkv_gemm_kernel<<<3072, 256, 0, stream>>>(wqb, wkb, wvb, qb, kb, vb, xn_t, qt, kt, vt);
  attn_kernel<<<256, 256, 0, stream>>>(qt, kt, vt, ot);
  proj_kernel<<<1024, 256, 0, stream>>>(wpb, pb, ot, x, out);
}